// Round 4
// baseline (240.874 us; speedup 1.0000x reference)
//
#include <hip/hip_runtime.h>
#include <stdint.h>

#define Bb 2
#define Ss 2048
#define Ee 1024
#define Hh 16
#define Dd 64

typedef __bf16 bf16;
typedef __attribute__((ext_vector_type(8))) __bf16 bf16x8;
typedef __attribute__((ext_vector_type(4))) __bf16 bf16x4;
typedef __attribute__((ext_vector_type(4))) float f32x4;

#define MB (1u << 20)
// workspace layout (bf16 regions), total 64 MB
#define OFF_XQ 0u
#define OFF_XK (8u * MB)
#define OFF_XV (16u * MB)
#define OFF_WQ (24u * MB)
#define OFF_WK (26u * MB)
#define OFF_WV (28u * MB)
#define OFF_WO (30u * MB)
#define OFF_Q  (32u * MB)   // [B,H,S,D], prescaled by c1/8 (c1 = +-log2e per indicator)
#define OFF_K  (40u * MB)   // [B,H,S,D]
#define OFF_VT (48u * MB)   // [B,H,D,S]  (transposed V)
#define OFF_AO (56u * MB)   // [B*S, E] attention output

__device__ __forceinline__ void gll16(const void* g, void* lds) {
  __builtin_amdgcn_global_load_lds(
      (const __attribute__((address_space(1))) void*)g,
      (__attribute__((address_space(3))) void*)lds, 16, 0, 0);
}

__device__ __forceinline__ unsigned pkbf(float lo, float hi) {
  unsigned r;
  asm("v_cvt_pk_bf16_f32 %0, %1, %2" : "=v"(r) : "v"(lo), "v"(hi));
  return r;
}
#define PL32SWAP(a, b) asm("v_permlane32_swap_b32 %0, %1" : "+v"(a), "+v"(b))
#define PL16SWAP(a, b) asm("v_permlane16_swap_b32 %0, %1" : "+v"(a), "+v"(b))

// ---------------- convert fp32 -> bf16 (Wq scaled by c1/8) ----------------
__global__ __launch_bounds__(256) void convert_kernel(
    const float* __restrict__ q, const float* __restrict__ k, const float* __restrict__ v,
    const float* __restrict__ wq, const float* __restrict__ wk, const float* __restrict__ wv,
    const float* __restrict__ wo, const int* __restrict__ ind, char* __restrict__ ws)
{
  const unsigned i = blockIdx.x * 256u + threadIdx.x;  // float4 units, 4194304 total
  const float* src;
  bf16* dst;
  float scale = 1.0f;
  if (i < 3145728u) {                      // queries/keys/values: 1M float4 each
    const unsigned a = i >> 20, j = i & 1048575u;
    src = (a == 0 ? q : a == 1 ? k : v) + (size_t)j * 4;
    dst = (bf16*)(ws + (size_t)a * (8u * MB)) + (size_t)j * 4;
  } else {                                 // Wq,Wk,Wv,Wo: 256K float4 each
    const unsigned i2 = i - 3145728u;
    const unsigned a = i2 >> 18, j = i2 & 262143u;
    src = (a == 0 ? wq : a == 1 ? wk : a == 2 ? wv : wo) + (size_t)j * 4;
    dst = (bf16*)(ws + OFF_WQ + (size_t)a * (2u * MB)) + (size_t)j * 4;
    if (a == 0) {                          // fold 1/sqrt(D) and +-log2e into Wq
      const float c1v = (*ind != 0) ? 1.442695041f : -1.442695041f;
      scale = 0.125f * c1v;
    }
  }
  const float4 f = *(const float4*)src;
  bf16x4 o;
  o[0] = (bf16)(f.x * scale);
  o[1] = (bf16)(f.y * scale);
  o[2] = (bf16)(f.z * scale);
  o[3] = (bf16)(f.w * scale);
  *(bf16x4*)dst = o;
}

// ---------------- shared 128x128x1024 bf16 GEMM body (C = A * W^T) ----------------
// TR=false: acc[mi][ni] = D[m in-lane][n = lane&15]
// TR=true : operands swapped -> acc[mi][ni] = D[n in-lane][m = lane&15] (C^T layout)
template <bool TR>
__device__ __forceinline__ void gemm128_body(
    const bf16* __restrict__ A, const bf16* __restrict__ W,
    char* smem, int m0, int n0, int t, f32x4 (&acc)[4][4])
{
  char* As = smem;
  char* Bs = smem + 16384;
  const int lane = t & 63;
  const int wid = t >> 6;
  const int wm = (wid >> 1) << 6;   // wave sub-tile origin
  const int wn = (wid & 1) << 6;
  for (int kt = 0; kt < 1024; kt += 64) {
    __syncthreads();
#pragma unroll
    for (int i = 0; i < 4; ++i) {
      const int L = i * 4096 + t * 16;        // linear LDS byte offset
      const int r = L >> 7;                   // tile row (128B rows)
      const int c = ((L >> 4) & 7) ^ (r & 7); // logical 16B chunk (pre-swizzled source)
      gll16(A + (size_t)(m0 + r) * 1024 + kt + c * 8, As + i * 4096 + wid * 1024);
      gll16(W + (size_t)(n0 + r) * 1024 + kt + c * 8, Bs + i * 4096 + wid * 1024);
    }
    __syncthreads();
#pragma unroll
    for (int ks = 0; ks < 2; ++ks) {
      bf16x8 af[4], bff[4];
#pragma unroll
      for (int mi = 0; mi < 4; ++mi) {
        const int r = wm + mi * 16 + (lane & 15);
        const int c = (ks * 4 + (lane >> 4)) ^ (r & 7);
        af[mi] = *(const bf16x8*)(As + r * 128 + c * 16);
      }
#pragma unroll
      for (int ni = 0; ni < 4; ++ni) {
        const int r = wn + ni * 16 + (lane & 15);
        const int c = (ks * 4 + (lane >> 4)) ^ (r & 7);
        bff[ni] = *(const bf16x8*)(Bs + r * 128 + c * 16);
      }
      __builtin_amdgcn_s_setprio(1);
#pragma unroll
      for (int mi = 0; mi < 4; ++mi)
#pragma unroll
        for (int ni = 0; ni < 4; ++ni) {
          if (TR)
            acc[mi][ni] = __builtin_amdgcn_mfma_f32_16x16x32_bf16(bff[ni], af[mi], acc[mi][ni], 0, 0, 0);
          else
            acc[mi][ni] = __builtin_amdgcn_mfma_f32_16x16x32_bf16(af[mi], bff[ni], acc[mi][ni], 0, 0, 0);
        }
      __builtin_amdgcn_s_setprio(0);
    }
  }
}

// ---------------- fused Q/K/V projection (grid.z selects q/k/v) ----------------
__global__ __launch_bounds__(256) void proj_gemm(
    char* __restrict__ ws, const float* __restrict__ bq,
    const float* __restrict__ bk, const float* __restrict__ bv,
    const int* __restrict__ ind)
{
  __shared__ __align__(16) char smem[32768];
  const int zi = blockIdx.z;
  const bf16* A = (const bf16*)(ws + (zi == 0 ? OFF_XQ : zi == 1 ? OFF_XK : OFF_XV));
  const bf16* W = (const bf16*)(ws + (zi == 0 ? OFF_WQ : zi == 1 ? OFF_WK : OFF_WV));
  const float* bias = zi == 0 ? bq : zi == 1 ? bk : bv;
  bf16* outp = (bf16*)(ws + (zi == 0 ? OFF_Q : zi == 1 ? OFF_K : OFF_VT));
  const float c1v = (*ind != 0) ? 1.442695041f : -1.442695041f;
  const float bscale = (zi == 0) ? 0.125f * c1v : 1.0f;
  const int t = threadIdx.x;
  const int m0 = blockIdx.y * 128, n0 = blockIdx.x * 128;
  const int lane = t & 63, wid = t >> 6;
  const int wm = (wid >> 1) << 6, wn = (wid & 1) << 6;
  const int l15 = lane & 15, g = lane >> 4;
  f32x4 acc[4][4] = {};
  if (zi == 2) {
    // V: normal orientation (in-lane = token), store transposed [B,H,D,S] as 8B runs
    gemm128_body<false>(A, W, smem, m0, n0, t, acc);
#pragma unroll
    for (int ni = 0; ni < 4; ++ni) {
      const int col = n0 + wn + ni * 16 + l15;
      const float bvv = bias[col];
      const int h = col >> 6, d = col & 63;
#pragma unroll
      for (int mi = 0; mi < 4; ++mi) {
        const int row0 = m0 + wm + mi * 16 + g * 4;  // token index (r2=0)
        const int b = row0 >> 11, s = row0 & 2047;
        bf16x4 o;
#pragma unroll
        for (int r2 = 0; r2 < 4; ++r2) o[r2] = (bf16)(acc[mi][ni][r2] + bvv);
        *(bf16x4*)&outp[((size_t)((b * Hh + h) * Dd + d) * Ss) + s] = o;
      }
    }
  } else {
    // Q/K: transposed orientation (in-lane = output col), store [B,H,S,D] as 8B runs
    gemm128_body<true>(A, W, smem, m0, n0, t, acc);
#pragma unroll
    for (int mi = 0; mi < 4; ++mi) {
      const int row = m0 + wm + mi * 16 + l15;   // token
      const int b = row >> 11, s = row & 2047;
#pragma unroll
      for (int ni = 0; ni < 4; ++ni) {
        const int col0 = n0 + wn + ni * 16 + g * 4;
        const int h = col0 >> 6, d0 = col0 & 63;
        const float4 b4 = *(const float4*)&bias[col0];
        bf16x4 o;
        o[0] = (bf16)(acc[mi][ni][0] + b4.x * bscale);
        o[1] = (bf16)(acc[mi][ni][1] + b4.y * bscale);
        o[2] = (bf16)(acc[mi][ni][2] + b4.z * bscale);
        o[3] = (bf16)(acc[mi][ni][3] + b4.w * bscale);
        *(bf16x4*)&outp[((size_t)((b * Hh + h) * Ss + s) * Dd) + d0] = o;
      }
    }
  }
}

// ---------------- attention: softmax(sigmoid(QK^T/8)) @ V ----------------
// 1024 blocks (XCD-clustered), 4 waves x 16 q-rows, q-tile 64. K/V in 32KB LDS,
// Q fragments straight from global. Swapped QK^T; P in registers; row sums via
// ones-MFMA. p = exp2(rcp(ln2 + exp2(st))), st init log2(ln2).
__global__ __launch_bounds__(256, 4) void attn_kernel(char* __restrict__ ws)
{
  __shared__ __align__(16) char smem[32768];
  char* Ks  = smem;            // [128 kv][64 d], 128B rows, swz chunk^(r&7)  (16KB)
  char* Vts = smem + 16384;    // [64 d][128 kv], 256B rows, swz (r&15)       (16KB)
  char* Os  = smem;            // output stage reuses Ks region (8KB)
  const int t = threadIdx.x, lane = t & 63, wid = t >> 6;
  const int g = lane >> 4, l15 = lane & 15;
  // XCD-clustered decode: xcd = lin%8 serves bh in [xcd*4, xcd*4+4) -> K/V L2-resident
  const int lin = blockIdx.x;
  const int bh = ((lin & 7) << 2) + ((lin >> 3) & 3);
  const int q0 = (lin >> 5) << 6;
  const bf16* Qg  = (const bf16*)(ws + OFF_Q)  + (size_t)bh * Ss * Dd;
  const bf16* Kg  = (const bf16*)(ws + OFF_K)  + (size_t)bh * Ss * Dd;
  const bf16* Vtg = (const bf16*)(ws + OFF_VT) + (size_t)bh * Ss * Dd;
  bf16* AO = (bf16*)(ws + OFF_AO);

  // Q fragments (B operand of swapped mfma) straight from global
  bf16x8 qf[2];
#pragma unroll
  for (int ks = 0; ks < 2; ++ks)
    qf[ks] = *(const bf16x8*)(Qg + (size_t)(q0 + wid * 16 + l15) * Dd + ks * 32 + g * 8);

  f32x4 acc_o[4] = {};   // Ot[d][q]: d = dblk*16+g*4+r2, q = l15 (wave q-base wid*16)
  f32x4 acc_sum = {};    // row sums via ones-MFMA
  union { unsigned u[4]; bf16x8 v; } ones_;
#pragma unroll
  for (int j = 0; j < 4; ++j) ones_.u[j] = 0x3F803F80u;  // bf16 1.0 pairs

  for (int kt = 0; kt < Ss; kt += 128) {
    __syncthreads();
    // stage K tile [128 kv][64 d]
#pragma unroll
    for (int i = 0; i < 4; ++i) {
      const int L = i * 4096 + t * 16;
      const int r = L >> 7;
      const int c = ((L >> 4) & 7) ^ (r & 7);
      gll16(Kg + (size_t)(kt + r) * Dd + c * 8, Ks + i * 4096 + wid * 1024);
    }
    // stage Vt tile [64 d][128 kv]
#pragma unroll
    for (int i = 0; i < 4; ++i) {
      const int L = i * 4096 + t * 16;
      const int r = L >> 8;
      const int c = ((L >> 4) & 15) ^ (r & 15);
      gll16(Vtg + (size_t)r * Ss + kt + c * 8, Vts + i * 4096 + wid * 1024);
    }
    __syncthreads();

    // St = K Q^T : St[kv][q], kv = ni*16 + g*4 + r2, q = l15; init log2(ln2)
    f32x4 st[8];
#pragma unroll
    for (int ni = 0; ni < 8; ++ni)
      st[ni] = (f32x4){-0.52876637f, -0.52876637f, -0.52876637f, -0.52876637f};
    __builtin_amdgcn_s_setprio(1);
#pragma unroll
    for (int ks = 0; ks < 2; ++ks) {
#pragma unroll
      for (int ni = 0; ni < 8; ++ni) {
        const int r = ni * 16 + l15;
        const int c = (ks * 4 + g) ^ (r & 7);
        const bf16x8 kf = *(const bf16x8*)(Ks + r * 128 + c * 16);
        st[ni] = __builtin_amdgcn_mfma_f32_16x16x32_bf16(kf, qf[ks], st[ni], 0, 0, 0);
      }
    }
    __builtin_amdgcn_s_setprio(0);

    // per 32-kv block: p = exp2(rcp(ln2 + exp2(st))); pack; permlane into PV B-frag
#pragma unroll
    for (int kb = 0; kb < 4; ++kb) {
      float p[2][4];
#pragma unroll
      for (int e = 0; e < 2; ++e)
#pragma unroll
        for (int r2 = 0; r2 < 4; ++r2) {
          const float ex = __builtin_amdgcn_exp2f(st[2 * kb + e][r2]);
          const float tt = __builtin_amdgcn_rcpf(0.69314718f + ex);
          p[e][r2] = __builtin_amdgcn_exp2f(tt);
        }
      unsigned E0 = pkbf(p[0][0], p[0][1]);
      unsigned E1 = pkbf(p[0][2], p[0][3]);
      unsigned O0 = pkbf(p[1][0], p[1][1]);
      unsigned O1 = pkbf(p[1][2], p[1][3]);
      PL32SWAP(E0, O0);
      PL16SWAP(E0, O0);
      PL32SWAP(E1, O1);
      PL16SWAP(E1, O1);
      union { unsigned u[4]; bf16x8 v; } pb;
      pb.u[0] = E0; pb.u[1] = E1; pb.u[2] = O0; pb.u[3] = O1;
      __builtin_amdgcn_s_setprio(1);
#pragma unroll
      for (int dblk = 0; dblk < 4; ++dblk) {
        const int r = dblk * 16 + l15;
        const int c = (kb * 4 + g) ^ (r & 15);
        const bf16x8 vf = *(const bf16x8*)(Vts + r * 256 + c * 16);
        acc_o[dblk] = __builtin_amdgcn_mfma_f32_16x16x32_bf16(vf, pb.v, acc_o[dblk], 0, 0, 0);
      }
      acc_sum = __builtin_amdgcn_mfma_f32_16x16x32_bf16(ones_.v, pb.v, acc_sum, 0, 0, 0);
      __builtin_amdgcn_s_setprio(0);
    }
  }

  const float rinv = __builtin_amdgcn_rcpf(acc_sum[0]);

  // stage Ot -> Os [64 q][64 d] (swizzled), then coalesced global write
  __syncthreads();  // all waves done reading Ks/Vts
  {
    const int row = wid * 16 + l15;          // q within tile
#pragma unroll
    for (int dblk = 0; dblk < 4; ++dblk) {
      const unsigned w0 = pkbf(acc_o[dblk][0] * rinv, acc_o[dblk][1] * rinv);
      const unsigned w1 = pkbf(acc_o[dblk][2] * rinv, acc_o[dblk][3] * rinv);
      const int cc = dblk * 2 + (g >> 1);    // 16B chunk of d*2 bytes
      char* a = Os + row * 128 + (cc ^ (row & 7)) * 16 + (g & 1) * 8;
      *(uint2*)a = make_uint2(w0, w1);
    }
  }
  __syncthreads();
  const int b = bh >> 4, h = bh & 15;
#pragma unroll
  for (int i = 0; i < 2; ++i) {
    const int L = i * 4096 + t * 16;
    const int r = L >> 7;                    // q row
    const int cc = (L >> 4) & 7;             // logical chunk (d*2 bytes /16)
    const uint4 w = *(const uint4*)(Os + r * 128 + (cc ^ (r & 7)) * 16);
    *(uint4*)&AO[((size_t)(b * Ss + q0 + r) << 10) + h * 64 + cc * 8] = w;
  }
}

// ---------------- output projection: d_out = AO @ Wo^T + bo (fp32 out) ----------------
// 128x64 tiles -> 512 blocks; transposed orientation -> float4 row-run stores.
__global__ __launch_bounds__(256) void out_gemm(char* __restrict__ ws,
                                                const float* __restrict__ bo,
                                                float* __restrict__ outp)
{
  __shared__ __align__(16) char smem[24576];
  char* As = smem;           // [128][64] bf16 (16KB)
  char* Bs = smem + 16384;   // [64][64] bf16 (8KB)
  const bf16* A = (const bf16*)(ws + OFF_AO);
  const bf16* W = (const bf16*)(ws + OFF_WO);
  const int t = threadIdx.x, lane = t & 63, wid = t >> 6;
  const int l15 = lane & 15, g = lane >> 4;
  const int m0 = blockIdx.y * 128, n0 = blockIdx.x * 64;
  const int wm = (wid >> 1) << 6;   // 2 waves M x 2 waves N
  const int wn = (wid & 1) << 5;
  f32x4 acc[4][2] = {};
  for (int kt = 0; kt < 1024; kt += 64) {
    __syncthreads();
#pragma unroll
    for (int i = 0; i < 4; ++i) {
      const int L = i * 4096 + t * 16;
      const int r = L >> 7;
      const int c = ((L >> 4) & 7) ^ (r & 7);
      gll16(A + (size_t)(m0 + r) * 1024 + kt + c * 8, As + i * 4096 + wid * 1024);
    }
#pragma unroll
    for (int i = 0; i < 2; ++i) {
      const int L = i * 4096 + t * 16;
      const int r = L >> 7;
      const int c = ((L >> 4) & 7) ^ (r & 7);
      gll16(W + (size_t)(n0 + r) * 1024 + kt + c * 8, Bs + i * 4096 + wid * 1024);
    }
    __syncthreads();
#pragma unroll
    for (int ks = 0; ks < 2; ++ks) {
      bf16x8 af[4], bff[2];
#pragma unroll
      for (int mi = 0; mi < 4; ++mi) {
        const int r = wm + mi * 16 + l15;
        const int c = (ks * 4 + g) ^ (r & 7);
        af[mi] = *(const bf16x8*)(As + r * 128 + c * 16);
      }
#pragma unroll
      for (int ni = 0; ni < 2; ++ni) {
        const int r = wn + ni * 16 + l15;
        const int c = (ks * 4 + g) ^ (r & 7);
        bff[ni] = *(const bf16x8*)(Bs + r * 128 + c * 16);
      }
      __builtin_amdgcn_s_setprio(1);
#pragma unroll
      for (int mi = 0; mi < 4; ++mi)
#pragma unroll
        for (int ni = 0; ni < 2; ++ni)
          acc[mi][ni] = __builtin_amdgcn_mfma_f32_16x16x32_bf16(bff[ni], af[mi], acc[mi][ni], 0, 0, 0);
      __builtin_amdgcn_s_setprio(0);
    }
  }
  // transposed layout: lane&15 = row (token), in-lane = 4 consecutive cols
#pragma unroll
  for (int mi = 0; mi < 4; ++mi) {
    const int row = m0 + wm + mi * 16 + l15;
#pragma unroll
    for (int ni = 0; ni < 2; ++ni) {
      const int col0 = n0 + wn + ni * 16 + g * 4;
      const float4 b4 = *(const float4*)&bo[col0];
      float4 o;
      o.x = acc[mi][ni][0] + b4.x;
      o.y = acc[mi][ni][1] + b4.y;
      o.z = acc[mi][ni][2] + b4.z;
      o.w = acc[mi][ni][3] + b4.w;
      *(float4*)&outp[(size_t)row * Ee + col0] = o;
    }
  }
}

extern "C" void kernel_launch(void* const* d_in, const int* in_sizes, int n_in,
                              void* d_out, int out_size, void* d_ws, size_t ws_size,
                              hipStream_t stream) {
  (void)in_sizes; (void)n_in; (void)out_size; (void)ws_size;
  const float* queries = (const float*)d_in[0];
  const float* keys    = (const float*)d_in[1];
  const float* values  = (const float*)d_in[2];
  const float* Wq = (const float*)d_in[3];
  const float* bq = (const float*)d_in[4];
  const float* Wk = (const float*)d_in[5];
  const float* bk = (const float*)d_in[6];
  const float* Wv = (const float*)d_in[7];
  const float* bv = (const float*)d_in[8];
  const float* Wo = (const float*)d_in[9];
  const float* bo = (const float*)d_in[10];
  const int* indicator = (const int*)d_in[11];
  char* ws = (char*)d_ws;
  float* outp = (float*)d_out;

  convert_kernel<<<16384, 256, 0, stream>>>(queries, keys, values, Wq, Wk, Wv, Wo, indicator, ws);
  proj_gemm<<<dim3(8, 32, 3), 256, 0, stream>>>(ws, bq, bk, bv, indicator);
  attn_kernel<<<1024, 256, 0, stream>>>(ws);
  out_gemm<<<dim3(16, 32), 256, 0, stream>>>(ws, bo, outp);
}

// Round 5
// 233.011 us; speedup vs baseline: 1.0337x; 1.0337x over previous
//
#include <hip/hip_runtime.h>
#include <stdint.h>

#define Bb 2
#define Ss 2048
#define Ee 1024
#define Hh 16
#define Dd 64

typedef __bf16 bf16;
typedef __attribute__((ext_vector_type(8))) __bf16 bf16x8;
typedef __attribute__((ext_vector_type(4))) __bf16 bf16x4;
typedef __attribute__((ext_vector_type(4))) float f32x4;

#define MB (1u << 20)
// workspace layout (bf16 regions), total 64 MB
#define OFF_XQ 0u
#define OFF_XK (8u * MB)
#define OFF_XV (16u * MB)
#define OFF_WQ (24u * MB)
#define OFF_WK (26u * MB)
#define OFF_WV (28u * MB)
#define OFF_WO (30u * MB)
#define OFF_Q  (32u * MB)   // [B,H,S,D], prescaled by c1/8 (c1 = +-log2e per indicator)
#define OFF_K  (40u * MB)   // [B,H,S,D]
#define OFF_VT (48u * MB)   // [B,H,D,S]  (transposed V)
#define OFF_AO (56u * MB)   // [B*S, E] attention output

__device__ __forceinline__ void gll16(const void* g, void* lds) {
  __builtin_amdgcn_global_load_lds(
      (const __attribute__((address_space(1))) void*)g,
      (__attribute__((address_space(3))) void*)lds, 16, 0, 0);
}

__device__ __forceinline__ unsigned pkbf(float lo, float hi) {
  unsigned r;
  asm("v_cvt_pk_bf16_f32 %0, %1, %2" : "=v"(r) : "v"(lo), "v"(hi));
  return r;
}
#define PL32SWAP(a, b) asm("v_permlane32_swap_b32 %0, %1" : "+v"(a), "+v"(b))
#define PL16SWAP(a, b) asm("v_permlane16_swap_b32 %0, %1" : "+v"(a), "+v"(b))

// ---------------- convert fp32 -> bf16 (Wq scaled by c1/8), grid-stride x4 ----------------
__global__ __launch_bounds__(256) void convert_kernel(
    const float* __restrict__ q, const float* __restrict__ k, const float* __restrict__ v,
    const float* __restrict__ wq, const float* __restrict__ wk, const float* __restrict__ wv,
    const float* __restrict__ wo, const int* __restrict__ ind, char* __restrict__ ws)
{
  const unsigned base = blockIdx.x * 256u + threadIdx.x;
#pragma unroll
  for (unsigned it = 0; it < 4; ++it) {
    const unsigned i = base + it * 1048576u;   // float4 units, 4194304 total
    const float* src;
    bf16* dst;
    float scale = 1.0f;
    if (i < 3145728u) {                      // queries/keys/values: 1M float4 each
      const unsigned a = i >> 20, j = i & 1048575u;
      src = (a == 0 ? q : a == 1 ? k : v) + (size_t)j * 4;
      dst = (bf16*)(ws + (size_t)a * (8u * MB)) + (size_t)j * 4;
    } else {                                 // Wq,Wk,Wv,Wo: 256K float4 each
      const unsigned i2 = i - 3145728u;
      const unsigned a = i2 >> 18, j = i2 & 262143u;
      src = (a == 0 ? wq : a == 1 ? wk : a == 2 ? wv : wo) + (size_t)j * 4;
      dst = (bf16*)(ws + OFF_WQ + (size_t)a * (2u * MB)) + (size_t)j * 4;
      if (a == 0) {                          // fold 1/sqrt(D) and +-log2e into Wq
        const float c1v = (*ind != 0) ? 1.442695041f : -1.442695041f;
        scale = 0.125f * c1v;
      }
    }
    const float4 f = *(const float4*)src;
    bf16x4 o;
    o[0] = (bf16)(f.x * scale);
    o[1] = (bf16)(f.y * scale);
    o[2] = (bf16)(f.z * scale);
    o[3] = (bf16)(f.w * scale);
    *(bf16x4*)dst = o;
  }
}

// ---------------- shared 128x128x1024 bf16 GEMM body (C = A * W^T) ----------------
// TR=false: acc[mi][ni] = D[m in-lane][n = lane&15]
// TR=true : operands swapped -> acc[mi][ni] = D[n in-lane][m = lane&15] (C^T layout)
template <bool TR>
__device__ __forceinline__ void gemm128_body(
    const bf16* __restrict__ A, const bf16* __restrict__ W,
    char* smem, int m0, int n0, int t, f32x4 (&acc)[4][4])
{
  char* As = smem;
  char* Bs = smem + 16384;
  const int lane = t & 63;
  const int wid = t >> 6;
  const int wm = (wid >> 1) << 6;   // wave sub-tile origin
  const int wn = (wid & 1) << 6;
  for (int kt = 0; kt < 1024; kt += 64) {
    __syncthreads();
#pragma unroll
    for (int i = 0; i < 4; ++i) {
      const int L = i * 4096 + t * 16;        // linear LDS byte offset
      const int r = L >> 7;                   // tile row (128B rows)
      const int c = ((L >> 4) & 7) ^ (r & 7); // logical 16B chunk (pre-swizzled source)
      gll16(A + (size_t)(m0 + r) * 1024 + kt + c * 8, As + i * 4096 + wid * 1024);
      gll16(W + (size_t)(n0 + r) * 1024 + kt + c * 8, Bs + i * 4096 + wid * 1024);
    }
    __syncthreads();
#pragma unroll
    for (int ks = 0; ks < 2; ++ks) {
      bf16x8 af[4], bff[4];
#pragma unroll
      for (int mi = 0; mi < 4; ++mi) {
        const int r = wm + mi * 16 + (lane & 15);
        const int c = (ks * 4 + (lane >> 4)) ^ (r & 7);
        af[mi] = *(const bf16x8*)(As + r * 128 + c * 16);
      }
#pragma unroll
      for (int ni = 0; ni < 4; ++ni) {
        const int r = wn + ni * 16 + (lane & 15);
        const int c = (ks * 4 + (lane >> 4)) ^ (r & 7);
        bff[ni] = *(const bf16x8*)(Bs + r * 128 + c * 16);
      }
      __builtin_amdgcn_s_setprio(1);
#pragma unroll
      for (int mi = 0; mi < 4; ++mi)
#pragma unroll
        for (int ni = 0; ni < 4; ++ni) {
          if (TR)
            acc[mi][ni] = __builtin_amdgcn_mfma_f32_16x16x32_bf16(bff[ni], af[mi], acc[mi][ni], 0, 0, 0);
          else
            acc[mi][ni] = __builtin_amdgcn_mfma_f32_16x16x32_bf16(af[mi], bff[ni], acc[mi][ni], 0, 0, 0);
        }
      __builtin_amdgcn_s_setprio(0);
    }
  }
}

// ---------------- fused Q/K/V projection (grid.z selects q/k/v) ----------------
// XCD-bijective swizzle: each XCD works 4 contiguous A-panels x all B panels.
__global__ __launch_bounds__(256) void proj_gemm(
    char* __restrict__ ws, const float* __restrict__ bq,
    const float* __restrict__ bk, const float* __restrict__ bv,
    const int* __restrict__ ind)
{
  __shared__ __align__(16) char smem[32768];
  const int zi = blockIdx.z;
  const bf16* A = (const bf16*)(ws + (zi == 0 ? OFF_XQ : zi == 1 ? OFF_XK : OFF_XV));
  const bf16* W = (const bf16*)(ws + (zi == 0 ? OFF_WQ : zi == 1 ? OFF_WK : OFF_WV));
  const float* bias = zi == 0 ? bq : zi == 1 ? bk : bv;
  bf16* outp = (bf16*)(ws + (zi == 0 ? OFF_Q : zi == 1 ? OFF_K : OFF_VT));
  const float c1v = (*ind != 0) ? 1.442695041f : -1.442695041f;
  const float bscale = (zi == 0) ? 0.125f * c1v : 1.0f;
  const int t = threadIdx.x;
  // swizzle: 256 wgs/z, xcd = wgid&7 gets nw in [xcd*32, xcd*32+32)
  const int wgid = blockIdx.x + blockIdx.y * 8;
  const int nw = (wgid & 7) * 32 + (wgid >> 3);
  const int m0 = (nw >> 3) * 128, n0 = (nw & 7) * 128;
  const int lane = t & 63, wid = t >> 6;
  const int wm = (wid >> 1) << 6, wn = (wid & 1) << 6;
  const int l15 = lane & 15, g = lane >> 4;
  f32x4 acc[4][4] = {};
  if (zi == 2) {
    // V: normal orientation (in-lane = token), store transposed [B,H,D,S] as 8B runs
    gemm128_body<false>(A, W, smem, m0, n0, t, acc);
#pragma unroll
    for (int ni = 0; ni < 4; ++ni) {
      const int col = n0 + wn + ni * 16 + l15;
      const float bvv = bias[col];
      const int h = col >> 6, d = col & 63;
#pragma unroll
      for (int mi = 0; mi < 4; ++mi) {
        const int row0 = m0 + wm + mi * 16 + g * 4;  // token index (r2=0)
        const int b = row0 >> 11, s = row0 & 2047;
        bf16x4 o;
#pragma unroll
        for (int r2 = 0; r2 < 4; ++r2) o[r2] = (bf16)(acc[mi][ni][r2] + bvv);
        *(bf16x4*)&outp[((size_t)((b * Hh + h) * Dd + d) * Ss) + s] = o;
      }
    }
  } else {
    // Q/K: transposed orientation (in-lane = output col), store [B,H,S,D] as 8B runs
    gemm128_body<true>(A, W, smem, m0, n0, t, acc);
#pragma unroll
    for (int mi = 0; mi < 4; ++mi) {
      const int row = m0 + wm + mi * 16 + l15;   // token
      const int b = row >> 11, s = row & 2047;
#pragma unroll
      for (int ni = 0; ni < 4; ++ni) {
        const int col0 = n0 + wn + ni * 16 + g * 4;
        const int h = col0 >> 6, d0 = col0 & 63;
        const float4 b4 = *(const float4*)&bias[col0];
        bf16x4 o;
        o[0] = (bf16)(acc[mi][ni][0] + b4.x * bscale);
        o[1] = (bf16)(acc[mi][ni][1] + b4.y * bscale);
        o[2] = (bf16)(acc[mi][ni][2] + b4.z * bscale);
        o[3] = (bf16)(acc[mi][ni][3] + b4.w * bscale);
        *(bf16x4*)&outp[((size_t)((b * Hh + h) * Ss + s) * Dd) + d0] = o;
      }
    }
  }
}

// ---------------- attention: softmax(sigmoid(QK^T/8)) @ V ----------------
// 512 blocks (XCD-clustered), 4 waves x 32 q-rows (q-tile 128). K/V double-buffered
// (64KB LDS), ONE barrier per kv-tile: stage t+1 via gll16 before computing t.
// Swapped QK^T; P in registers; row sums via ones-MFMA.
__global__ __launch_bounds__(256, 2) void attn_kernel(char* __restrict__ ws)
{
  __shared__ __align__(16) char smem[65536];
  // buf b at smem + b*32768: K [128 kv][64 d] swz chunk^(r&7) (16KB); Vt [64 d][128 kv] swz (r&15) (16KB)
  char* Os = smem;             // output stage reuses buf0 K region (16KB) at the end
  const int t = threadIdx.x, lane = t & 63, wid = t >> 6;
  const int g = lane >> 4, l15 = lane & 15;
  // XCD-clustered decode: xcd = lin&7 serves bh in [xcd*4, xcd*4+4) -> K/V L2-resident
  const int lin = blockIdx.x;
  const int j = lin >> 3;
  const int bh = ((lin & 7) << 2) + (j & 3);
  const int q0 = (j >> 2) << 7;
  const bf16* Qg  = (const bf16*)(ws + OFF_Q)  + (size_t)bh * Ss * Dd;
  const bf16* Kg  = (const bf16*)(ws + OFF_K)  + (size_t)bh * Ss * Dd;
  const bf16* Vtg = (const bf16*)(ws + OFF_VT) + (size_t)bh * Ss * Dd;
  bf16* AO = (bf16*)(ws + OFF_AO);

  // Q fragments (B operand of swapped mfma) straight from global; wave covers 32 q-rows
  bf16x8 qf[2][2];
#pragma unroll
  for (int qh = 0; qh < 2; ++qh)
#pragma unroll
    for (int ks = 0; ks < 2; ++ks)
      qf[qh][ks] = *(const bf16x8*)(Qg + (size_t)(q0 + wid * 32 + qh * 16 + l15) * Dd + ks * 32 + g * 8);

  f32x4 acc_o[2][4] = {};   // [qh][dblk]: Ot[d][q], d = dblk*16+g*4+r2, q = l15
  f32x4 acc_sum[2] = {};    // row sums via ones-MFMA
  union { unsigned u[4]; bf16x8 v; } ones_;
#pragma unroll
  for (int jj = 0; jj < 4; ++jj) ones_.u[jj] = 0x3F803F80u;  // bf16 1.0 pairs

  // staging helper (macro to keep gll16 literals)
#define STAGE_KV(kt_, buf_)                                                         \
  {                                                                                  \
    char* Kb = (buf_);                                                               \
    char* Vb = (buf_) + 16384;                                                       \
    _Pragma("unroll")                                                                \
    for (int i = 0; i < 4; ++i) {                                                    \
      const int L = i * 4096 + t * 16;                                               \
      const int rk = L >> 7;                                                         \
      const int ck = ((L >> 4) & 7) ^ (rk & 7);                                      \
      gll16(Kg + (size_t)((kt_) + rk) * Dd + ck * 8, Kb + i * 4096 + wid * 1024);    \
      const int rv = L >> 8;                                                         \
      const int cv = ((L >> 4) & 15) ^ (rv & 15);                                    \
      gll16(Vtg + (size_t)rv * Ss + (kt_) + cv * 8, Vb + i * 4096 + wid * 1024);     \
    }                                                                                \
  }

  STAGE_KV(0, smem);
  __syncthreads();

  for (int ti = 0; ti < 16; ++ti) {
    char* cur = smem + (ti & 1) * 32768;
    char* nxt = smem + ((ti & 1) ^ 1) * 32768;
    if (ti < 15) STAGE_KV((ti + 1) * 128, nxt);
    char* Ks = cur;
    char* Vts = cur + 16384;

    // St = K Q^T : St[qh][kv][q], kv = ni*16 + g*4 + r2, q = l15; init log2(ln2)
    f32x4 st[2][8];
#pragma unroll
    for (int qh = 0; qh < 2; ++qh)
#pragma unroll
      for (int ni = 0; ni < 8; ++ni)
        st[qh][ni] = (f32x4){-0.52876637f, -0.52876637f, -0.52876637f, -0.52876637f};
    __builtin_amdgcn_s_setprio(1);
#pragma unroll
    for (int ks = 0; ks < 2; ++ks) {
#pragma unroll
      for (int ni = 0; ni < 8; ++ni) {
        const int r = ni * 16 + l15;
        const int c = (ks * 4 + g) ^ (r & 7);
        const bf16x8 kf = *(const bf16x8*)(Ks + r * 128 + c * 16);
        st[0][ni] = __builtin_amdgcn_mfma_f32_16x16x32_bf16(kf, qf[0][ks], st[0][ni], 0, 0, 0);
        st[1][ni] = __builtin_amdgcn_mfma_f32_16x16x32_bf16(kf, qf[1][ks], st[1][ni], 0, 0, 0);
      }
    }
    __builtin_amdgcn_s_setprio(0);

    // per 32-kv block: p = exp2(rcp(ln2 + exp2(st))); pack; permlane into PV B-frag
#pragma unroll
    for (int kb = 0; kb < 4; ++kb) {
      union { unsigned u[4]; bf16x8 v; } pb[2];
#pragma unroll
      for (int qh = 0; qh < 2; ++qh) {
        float p[2][4];
#pragma unroll
        for (int e = 0; e < 2; ++e)
#pragma unroll
          for (int r2 = 0; r2 < 4; ++r2) {
            const float ex = __builtin_amdgcn_exp2f(st[qh][2 * kb + e][r2]);
            const float tt = __builtin_amdgcn_rcpf(0.69314718f + ex);
            p[e][r2] = __builtin_amdgcn_exp2f(tt);
          }
        unsigned E0 = pkbf(p[0][0], p[0][1]);
        unsigned E1 = pkbf(p[0][2], p[0][3]);
        unsigned O0 = pkbf(p[1][0], p[1][1]);
        unsigned O1 = pkbf(p[1][2], p[1][3]);
        PL32SWAP(E0, O0);
        PL16SWAP(E0, O0);
        PL32SWAP(E1, O1);
        PL16SWAP(E1, O1);
        pb[qh].u[0] = E0; pb[qh].u[1] = E1; pb[qh].u[2] = O0; pb[qh].u[3] = O1;
      }
      __builtin_amdgcn_s_setprio(1);
#pragma unroll
      for (int dblk = 0; dblk < 4; ++dblk) {
        const int r = dblk * 16 + l15;
        const int c = (kb * 4 + g) ^ (r & 15);
        const bf16x8 vf = *(const bf16x8*)(Vts + r * 256 + c * 16);
        acc_o[0][dblk] = __builtin_amdgcn_mfma_f32_16x16x32_bf16(vf, pb[0].v, acc_o[0][dblk], 0, 0, 0);
        acc_o[1][dblk] = __builtin_amdgcn_mfma_f32_16x16x32_bf16(vf, pb[1].v, acc_o[1][dblk], 0, 0, 0);
      }
      acc_sum[0] = __builtin_amdgcn_mfma_f32_16x16x32_bf16(ones_.v, pb[0].v, acc_sum[0], 0, 0, 0);
      acc_sum[1] = __builtin_amdgcn_mfma_f32_16x16x32_bf16(ones_.v, pb[1].v, acc_sum[1], 0, 0, 0);
      __builtin_amdgcn_s_setprio(0);
    }
    __syncthreads();   // waves done with cur; nxt fully staged (vmcnt drained here)
  }
#undef STAGE_KV

  const float rinv[2] = {__builtin_amdgcn_rcpf(acc_sum[0][0]),
                         __builtin_amdgcn_rcpf(acc_sum[1][0])};

  // stage Ot -> Os [128 q][64 d] (swizzled), then coalesced global write
#pragma unroll
  for (int qh = 0; qh < 2; ++qh) {
    const int row = wid * 32 + qh * 16 + l15;
#pragma unroll
    for (int dblk = 0; dblk < 4; ++dblk) {
      const unsigned w0 = pkbf(acc_o[qh][dblk][0] * rinv[qh], acc_o[qh][dblk][1] * rinv[qh]);
      const unsigned w1 = pkbf(acc_o[qh][dblk][2] * rinv[qh], acc_o[qh][dblk][3] * rinv[qh]);
      const int cc = dblk * 2 + (g >> 1);    // 16B chunk of d*2 bytes
      char* a = Os + row * 128 + (cc ^ (row & 7)) * 16 + (g & 1) * 8;
      *(uint2*)a = make_uint2(w0, w1);
    }
  }
  __syncthreads();
  const int b = bh >> 4, h = bh & 15;
#pragma unroll
  for (int i = 0; i < 4; ++i) {
    const int L = i * 4096 + t * 16;
    const int r = L >> 7;                    // q row
    const int cc = (L >> 4) & 7;             // logical chunk (d*2 bytes /16)
    const uint4 w = *(const uint4*)(Os + r * 128 + (cc ^ (r & 7)) * 16);
    *(uint4*)&AO[((size_t)(b * Ss + q0 + r) << 10) + h * 64 + cc * 8] = w;
  }
}

// ---------------- output projection: d_out = AO @ Wo^T + bo (fp32 out) ----------------
// 128x64 tiles, 512 blocks, XCD-bijective swizzle; transposed orientation -> float4 stores.
__global__ __launch_bounds__(256) void out_gemm(char* __restrict__ ws,
                                                const float* __restrict__ bo,
                                                float* __restrict__ outp)
{
  __shared__ __align__(16) char smem[24576];
  char* As = smem;           // [128][64] bf16 (16KB)
  char* Bs = smem + 16384;   // [64][64] bf16 (8KB)
  const bf16* A = (const bf16*)(ws + OFF_AO);
  const bf16* W = (const bf16*)(ws + OFF_WO);
  const int t = threadIdx.x, lane = t & 63, wid = t >> 6;
  const int l15 = lane & 15, g = lane >> 4;
  // swizzle: 512 wgs, xcd = wgid&7 gets nw in [xcd*64, xcd*64+64)
  const int wgid = blockIdx.x + blockIdx.y * 16;
  const int nw = (wgid & 7) * 64 + (wgid >> 3);
  const int m0 = (nw >> 4) * 128, n0 = (nw & 15) * 64;
  const int wm = (wid >> 1) << 6;   // 2 waves M x 2 waves N
  const int wn = (wid & 1) << 5;
  f32x4 acc[4][2] = {};
  for (int kt = 0; kt < 1024; kt += 64) {
    __syncthreads();
#pragma unroll
    for (int i = 0; i < 4; ++i) {
      const int L = i * 4096 + t * 16;
      const int r = L >> 7;
      const int c = ((L >> 4) & 7) ^ (r & 7);
      gll16(A + (size_t)(m0 + r) * 1024 + kt + c * 8, As + i * 4096 + wid * 1024);
    }
#pragma unroll
    for (int i = 0; i < 2; ++i) {
      const int L = i * 4096 + t * 16;
      const int r = L >> 7;
      const int c = ((L >> 4) & 7) ^ (r & 7);
      gll16(W + (size_t)(n0 + r) * 1024 + kt + c * 8, Bs + i * 4096 + wid * 1024);
    }
    __syncthreads();
#pragma unroll
    for (int ks = 0; ks < 2; ++ks) {
      bf16x8 af[4], bff[2];
#pragma unroll
      for (int mi = 0; mi < 4; ++mi) {
        const int r = wm + mi * 16 + l15;
        const int c = (ks * 4 + g) ^ (r & 7);
        af[mi] = *(const bf16x8*)(As + r * 128 + c * 16);
      }
#pragma unroll
      for (int ni = 0; ni < 2; ++ni) {
        const int r = wn + ni * 16 + l15;
        const int c = (ks * 4 + g) ^ (r & 7);
        bff[ni] = *(const bf16x8*)(Bs + r * 128 + c * 16);
      }
      __builtin_amdgcn_s_setprio(1);
#pragma unroll
      for (int mi = 0; mi < 4; ++mi)
#pragma unroll
        for (int ni = 0; ni < 2; ++ni)
          acc[mi][ni] = __builtin_amdgcn_mfma_f32_16x16x32_bf16(bff[ni], af[mi], acc[mi][ni], 0, 0, 0);
      __builtin_amdgcn_s_setprio(0);
    }
  }
  // transposed layout: lane&15 = row (token), in-lane = 4 consecutive cols
#pragma unroll
  for (int mi = 0; mi < 4; ++mi) {
    const int row = m0 + wm + mi * 16 + l15;
#pragma unroll
    for (int ni = 0; ni < 2; ++ni) {
      const int col0 = n0 + wn + ni * 16 + g * 4;
      const float4 b4 = *(const float4*)&bo[col0];
      float4 o;
      o.x = acc[mi][ni][0] + b4.x;
      o.y = acc[mi][ni][1] + b4.y;
      o.z = acc[mi][ni][2] + b4.z;
      o.w = acc[mi][ni][3] + b4.w;
      *(float4*)&outp[(size_t)row * Ee + col0] = o;
    }
  }
}

extern "C" void kernel_launch(void* const* d_in, const int* in_sizes, int n_in,
                              void* d_out, int out_size, void* d_ws, size_t ws_size,
                              hipStream_t stream) {
  (void)in_sizes; (void)n_in; (void)out_size; (void)ws_size;
  const float* queries = (const float*)d_in[0];
  const float* keys    = (const float*)d_in[1];
  const float* values  = (const float*)d_in[2];
  const float* Wq = (const float*)d_in[3];
  const float* bq = (const float*)d_in[4];
  const float* Wk = (const float*)d_in[5];
  const float* bk = (const float*)d_in[6];
  const float* Wv = (const float*)d_in[7];
  const float* bv = (const float*)d_in[8];
  const float* Wo = (const float*)d_in[9];
  const float* bo = (const float*)d_in[10];
  const int* indicator = (const int*)d_in[11];
  char* ws = (char*)d_ws;
  float* outp = (float*)d_out;

  convert_kernel<<<4096, 256, 0, stream>>>(queries, keys, values, Wq, Wk, Wv, Wo, indicator, ws);
  proj_gemm<<<dim3(8, 32, 3), 256, 0, stream>>>(ws, bq, bk, bv, indicator);
  attn_kernel<<<512, 256, 0, stream>>>(ws);
  out_gemm<<<dim3(16, 32), 256, 0, stream>>>(ws, bo, outp);
}

// Round 7
// 232.250 us; speedup vs baseline: 1.0371x; 1.0033x over previous
//
#include <hip/hip_runtime.h>
#include <stdint.h>

#define Bb 2
#define Ss 2048
#define Ee 1024
#define Hh 16
#define Dd 64

typedef __bf16 bf16;
typedef __attribute__((ext_vector_type(8))) __bf16 bf16x8;
typedef __attribute__((ext_vector_type(4))) __bf16 bf16x4;
typedef __attribute__((ext_vector_type(4))) float f32x4;

#define MB (1u << 20)
// workspace layout (bf16 regions), total 64 MB
#define OFF_XQ 0u
#define OFF_XK (8u * MB)
#define OFF_XV (16u * MB)
#define OFF_WQ (24u * MB)
#define OFF_WK (26u * MB)
#define OFF_WV (28u * MB)
#define OFF_WO (30u * MB)
#define OFF_Q  (32u * MB)   // [B,H,S,D], prescaled by c1/8 (c1 = +-log2e per indicator)
#define OFF_K  (40u * MB)   // [B,H,S,D]
#define OFF_VT (48u * MB)   // [B,H,D,S]  (transposed V)
#define OFF_AO (56u * MB)   // [B*S, E] attention output

__device__ __forceinline__ void gll16(const void* g, void* lds) {
  __builtin_amdgcn_global_load_lds(
      (const __attribute__((address_space(1))) void*)g,
      (__attribute__((address_space(3))) void*)lds, 16, 0, 0);
}

__device__ __forceinline__ unsigned pkbf(float lo, float hi) {
  unsigned r;
  asm("v_cvt_pk_bf16_f32 %0, %1, %2" : "=v"(r) : "v"(lo), "v"(hi));
  return r;
}
#define PL32SWAP(a, b) asm("v_permlane32_swap_b32 %0, %1" : "+v"(a), "+v"(b))
#define PL16SWAP(a, b) asm("v_permlane16_swap_b32 %0, %1" : "+v"(a), "+v"(b))

// ---------------- convert fp32 -> bf16 (Wq scaled by c1/8), grid-stride x4 ----------------
__global__ __launch_bounds__(256) void convert_kernel(
    const float* __restrict__ q, const float* __restrict__ k, const float* __restrict__ v,
    const float* __restrict__ wq, const float* __restrict__ wk, const float* __restrict__ wv,
    const float* __restrict__ wo, const int* __restrict__ ind, char* __restrict__ ws)
{
  const unsigned base = blockIdx.x * 256u + threadIdx.x;
#pragma unroll
  for (unsigned it = 0; it < 4; ++it) {
    const unsigned i = base + it * 1048576u;   // float4 units, 4194304 total
    const float* src;
    bf16* dst;
    float scale = 1.0f;
    if (i < 3145728u) {                      // queries/keys/values: 1M float4 each
      const unsigned a = i >> 20, j = i & 1048575u;
      src = (a == 0 ? q : a == 1 ? k : v) + (size_t)j * 4;
      dst = (bf16*)(ws + (size_t)a * (8u * MB)) + (size_t)j * 4;
    } else {                                 // Wq,Wk,Wv,Wo: 256K float4 each
      const unsigned i2 = i - 3145728u;
      const unsigned a = i2 >> 18, j = i2 & 262143u;
      src = (a == 0 ? wq : a == 1 ? wk : a == 2 ? wv : wo) + (size_t)j * 4;
      dst = (bf16*)(ws + OFF_WQ + (size_t)a * (2u * MB)) + (size_t)j * 4;
      if (a == 0) {                          // fold 1/sqrt(D) and +-log2e into Wq
        const float c1v = (*ind != 0) ? 1.442695041f : -1.442695041f;
        scale = 0.125f * c1v;
      }
    }
    const float4 f = *(const float4*)src;
    bf16x4 o;
    o[0] = (bf16)(f.x * scale);
    o[1] = (bf16)(f.y * scale);
    o[2] = (bf16)(f.z * scale);
    o[3] = (bf16)(f.w * scale);
    *(bf16x4*)dst = o;
  }
}

// ---------------- 8-wave 128x128x1024 bf16 GEMM body (C = A * W^T) ----------------
// 512 threads; waves 4M x 2N, each owns 32x64. TR swaps MFMA operands (C^T layout).
template <bool TR>
__device__ __forceinline__ void gemm128_body8(
    const bf16* __restrict__ A, const bf16* __restrict__ W,
    char* smem, int m0, int n0, int t, f32x4 (&acc)[2][4])
{
  char* As = smem;
  char* Bs = smem + 16384;
  const int lane = t & 63;
  const int wid = t >> 6;
  const int wm = (wid >> 1) << 5;   // 4 M-waves x 32
  const int wn = (wid & 1) << 6;    // 2 N-waves x 64
  for (int kt = 0; kt < 1024; kt += 64) {
    __syncthreads();
#pragma unroll
    for (int i = 0; i < 2; ++i) {
      const int L = i * 8192 + t * 16;        // linear LDS byte offset
      const int r = L >> 7;                   // tile row (128B rows)
      const int c = ((L >> 4) & 7) ^ (r & 7); // logical 16B chunk (pre-swizzled source)
      gll16(A + (size_t)(m0 + r) * 1024 + kt + c * 8, As + i * 8192 + wid * 1024);
      gll16(W + (size_t)(n0 + r) * 1024 + kt + c * 8, Bs + i * 8192 + wid * 1024);
    }
    __syncthreads();
#pragma unroll
    for (int ks = 0; ks < 2; ++ks) {
      bf16x8 af[2], bff[4];
#pragma unroll
      for (int mi = 0; mi < 2; ++mi) {
        const int r = wm + mi * 16 + (lane & 15);
        const int c = (ks * 4 + (lane >> 4)) ^ (r & 7);
        af[mi] = *(const bf16x8*)(As + r * 128 + c * 16);
      }
#pragma unroll
      for (int ni = 0; ni < 4; ++ni) {
        const int r = wn + ni * 16 + (lane & 15);
        const int c = (ks * 4 + (lane >> 4)) ^ (r & 7);
        bff[ni] = *(const bf16x8*)(Bs + r * 128 + c * 16);
      }
      __builtin_amdgcn_s_setprio(1);
#pragma unroll
      for (int mi = 0; mi < 2; ++mi)
#pragma unroll
        for (int ni = 0; ni < 4; ++ni) {
          if (TR)
            acc[mi][ni] = __builtin_amdgcn_mfma_f32_16x16x32_bf16(bff[ni], af[mi], acc[mi][ni], 0, 0, 0);
          else
            acc[mi][ni] = __builtin_amdgcn_mfma_f32_16x16x32_bf16(af[mi], bff[ni], acc[mi][ni], 0, 0, 0);
        }
      __builtin_amdgcn_s_setprio(0);
    }
  }
}

// ---------------- fused Q/K/V projection (grid.z selects q/k/v), 512 threads ----------------
__global__ __launch_bounds__(512) void proj_gemm(
    char* __restrict__ ws, const float* __restrict__ bq,
    const float* __restrict__ bk, const float* __restrict__ bv,
    const int* __restrict__ ind)
{
  __shared__ __align__(16) char smem[32768];
  const int zi = blockIdx.z;
  const bf16* A = (const bf16*)(ws + (zi == 0 ? OFF_XQ : zi == 1 ? OFF_XK : OFF_XV));
  const bf16* W = (const bf16*)(ws + (zi == 0 ? OFF_WQ : zi == 1 ? OFF_WK : OFF_WV));
  const float* bias = zi == 0 ? bq : zi == 1 ? bk : bv;
  bf16* outp = (bf16*)(ws + (zi == 0 ? OFF_Q : zi == 1 ? OFF_K : OFF_VT));
  const float c1v = (*ind != 0) ? 1.442695041f : -1.442695041f;
  const float bscale = (zi == 0) ? 0.125f * c1v : 1.0f;
  const int t = threadIdx.x;
  // swizzle: 256 wgs/z, xcd = wgid&7 gets nw in [xcd*32, xcd*32+32)
  const int wgid = blockIdx.x + blockIdx.y * 8;
  const int nw = (wgid & 7) * 32 + (wgid >> 3);
  const int m0 = (nw >> 3) * 128, n0 = (nw & 7) * 128;
  const int lane = t & 63, wid = t >> 6;
  const int wm = (wid >> 1) << 5, wn = (wid & 1) << 6;
  const int l15 = lane & 15, g = lane >> 4;
  f32x4 acc[2][4] = {};
  if (zi == 2) {
    // V: normal orientation (in-lane = token), store transposed [B,H,D,S] as 8B runs
    gemm128_body8<false>(A, W, smem, m0, n0, t, acc);
#pragma unroll
    for (int ni = 0; ni < 4; ++ni) {
      const int col = n0 + wn + ni * 16 + l15;
      const float bvv = bias[col];
      const int h = col >> 6, d = col & 63;
#pragma unroll
      for (int mi = 0; mi < 2; ++mi) {
        const int row0 = m0 + wm + mi * 16 + g * 4;  // token index (r2=0)
        const int b = row0 >> 11, s = row0 & 2047;
        bf16x4 o;
#pragma unroll
        for (int r2 = 0; r2 < 4; ++r2) o[r2] = (bf16)(acc[mi][ni][r2] + bvv);
        *(bf16x4*)&outp[((size_t)((b * Hh + h) * Dd + d) * Ss) + s] = o;
      }
    }
  } else {
    // Q/K: transposed orientation (in-lane = output col), store [B,H,S,D] as 8B runs
    gemm128_body8<true>(A, W, smem, m0, n0, t, acc);
#pragma unroll
    for (int mi = 0; mi < 2; ++mi) {
      const int row = m0 + wm + mi * 16 + l15;   // token
      const int b = row >> 11, s = row & 2047;
#pragma unroll
      for (int ni = 0; ni < 4; ++ni) {
        const int col0 = n0 + wn + ni * 16 + g * 4;
        const int h = col0 >> 6, d0 = col0 & 63;
        const float4 b4 = *(const float4*)&bias[col0];
        bf16x4 o;
        o[0] = (bf16)(acc[mi][ni][0] + b4.x * bscale);
        o[1] = (bf16)(acc[mi][ni][1] + b4.y * bscale);
        o[2] = (bf16)(acc[mi][ni][2] + b4.z * bscale);
        o[3] = (bf16)(acc[mi][ni][3] + b4.w * bscale);
        *(bf16x4*)&outp[((size_t)((b * Hh + h) * Ss + s) * Dd) + d0] = o;
      }
    }
  }
}

// ---------------- attention: softmax(sigmoid(QK^T/8)) @ V ----------------
// 512 blocks (XCD-clustered), 4 waves x 32 q-rows (q-tile 128). K/V double-buffered
// (64KB LDS) with COUNTED vmcnt: next tile's 8 gll16 stay in flight across the
// barrier (raw s_barrier, no vmcnt(0) drain). Swapped QK^T; P in registers.
__global__ __launch_bounds__(256, 2) void attn_kernel(char* __restrict__ ws)
{
  __shared__ __align__(16) char smem[65536];
  // buf b at smem + b*32768: K [128 kv][64 d] swz chunk^(r&7) (16KB); Vt [64 d][128 kv] swz (r&15) (16KB)
  char* Os = smem;             // output stage reuses buf0 K region (16KB) at the end
  const int t = threadIdx.x, lane = t & 63, wid = t >> 6;
  const int g = lane >> 4, l15 = lane & 15;
  // XCD-clustered decode: xcd = lin&7 serves bh in [xcd*4, xcd*4+4) -> K/V L2-resident
  const int lin = blockIdx.x;
  const int j = lin >> 3;
  const int bh = ((lin & 7) << 2) + (j & 3);
  const int q0 = (j >> 2) << 7;
  const bf16* Qg  = (const bf16*)(ws + OFF_Q)  + (size_t)bh * Ss * Dd;
  const bf16* Kg  = (const bf16*)(ws + OFF_K)  + (size_t)bh * Ss * Dd;
  const bf16* Vtg = (const bf16*)(ws + OFF_VT) + (size_t)bh * Ss * Dd;
  bf16* AO = (bf16*)(ws + OFF_AO);

  // Q fragments (B operand of swapped mfma) straight from global; wave covers 32 q-rows
  bf16x8 qf[2][2];
#pragma unroll
  for (int qh = 0; qh < 2; ++qh)
#pragma unroll
    for (int ks = 0; ks < 2; ++ks)
      qf[qh][ks] = *(const bf16x8*)(Qg + (size_t)(q0 + wid * 32 + qh * 16 + l15) * Dd + ks * 32 + g * 8);

  f32x4 acc_o[2][4] = {};   // [qh][dblk]: Ot[d][q], d = dblk*16+g*4+r2, q = l15
  f32x4 acc_sum[2] = {};    // row sums via ones-MFMA
  union { unsigned u[4]; bf16x8 v; } ones_;
#pragma unroll
  for (int jj = 0; jj < 4; ++jj) ones_.u[jj] = 0x3F803F80u;  // bf16 1.0 pairs

  // staging helper: 8 gll16 per thread (K tile + Vt tile)
#define STAGE_KV(kt_, buf_)                                                         \
  {                                                                                  \
    char* Kb = (buf_);                                                               \
    char* Vb = (buf_) + 16384;                                                       \
    _Pragma("unroll")                                                                \
    for (int i = 0; i < 4; ++i) {                                                    \
      const int L = i * 4096 + t * 16;                                               \
      const int rk = L >> 7;                                                         \
      const int ck = ((L >> 4) & 7) ^ (rk & 7);                                      \
      gll16(Kg + (size_t)((kt_) + rk) * Dd + ck * 8, Kb + i * 4096 + wid * 1024);    \
      const int rv = L >> 8;                                                         \
      const int cv = ((L >> 4) & 15) ^ (rv & 15);                                    \
      gll16(Vtg + (size_t)rv * Ss + (kt_) + cv * 8, Vb + i * 4096 + wid * 1024);     \
    }                                                                                \
  }

  STAGE_KV(0, smem);

  for (int ti = 0; ti < 16; ++ti) {
    char* cur = smem + (ti & 1) * 32768;
    char* nxt = smem + ((ti & 1) ^ 1) * 32768;
    if (ti < 15) {
      STAGE_KV((ti + 1) * 128, nxt);
      // wait only the 8 oldest (cur's) loads; nxt's 8 stay in flight across barrier
      asm volatile("s_waitcnt vmcnt(8)" ::: "memory");
    } else {
      asm volatile("s_waitcnt vmcnt(0)" ::: "memory");
    }
    __builtin_amdgcn_s_barrier();
    __builtin_amdgcn_sched_barrier(0);
    char* Ks = cur;
    char* Vts = cur + 16384;

    // St = K Q^T : St[qh][kv][q], kv = ni*16 + g*4 + r2, q = l15; init log2(ln2)
    f32x4 st[2][8];
#pragma unroll
    for (int qh = 0; qh < 2; ++qh)
#pragma unroll
      for (int ni = 0; ni < 8; ++ni)
        st[qh][ni] = (f32x4){-0.52876637f, -0.52876637f, -0.52876637f, -0.52876637f};
    __builtin_amdgcn_s_setprio(1);
#pragma unroll
    for (int ks = 0; ks < 2; ++ks) {
#pragma unroll
      for (int ni = 0; ni < 8; ++ni) {
        const int r = ni * 16 + l15;
        const int c = (ks * 4 + g) ^ (r & 7);
        const bf16x8 kf = *(const bf16x8*)(Ks + r * 128 + c * 16);
        st[0][ni] = __builtin_amdgcn_mfma_f32_16x16x32_bf16(kf, qf[0][ks], st[0][ni], 0, 0, 0);
        st[1][ni] = __builtin_amdgcn_mfma_f32_16x16x32_bf16(kf, qf[1][ks], st[1][ni], 0, 0, 0);
      }
    }
    __builtin_amdgcn_s_setprio(0);

    // per 32-kv block: p = exp2(rcp(ln2 + exp2(st))); pack; permlane into PV B-frag
#pragma unroll
    for (int kb = 0; kb < 4; ++kb) {
      union { unsigned u[4]; bf16x8 v; } pb[2];
#pragma unroll
      for (int qh = 0; qh < 2; ++qh) {
        float p[2][4];
#pragma unroll
        for (int e = 0; e < 2; ++e)
#pragma unroll
          for (int r2 = 0; r2 < 4; ++r2) {
            const float ex = __builtin_amdgcn_exp2f(st[qh][2 * kb + e][r2]);
            const float tt = __builtin_amdgcn_rcpf(0.69314718f + ex);
            p[e][r2] = __builtin_amdgcn_exp2f(tt);
          }
        unsigned E0 = pkbf(p[0][0], p[0][1]);
        unsigned E1 = pkbf(p[0][2], p[0][3]);
        unsigned O0 = pkbf(p[1][0], p[1][1]);
        unsigned O1 = pkbf(p[1][2], p[1][3]);
        PL32SWAP(E0, O0);
        PL16SWAP(E0, O0);
        PL32SWAP(E1, O1);
        PL16SWAP(E1, O1);
        pb[qh].u[0] = E0; pb[qh].u[1] = E1; pb[qh].u[2] = O0; pb[qh].u[3] = O1;
      }
      __builtin_amdgcn_s_setprio(1);
#pragma unroll
      for (int dblk = 0; dblk < 4; ++dblk) {
        const int r = dblk * 16 + l15;
        const int c = (kb * 4 + g) ^ (r & 15);
        const bf16x8 vf = *(const bf16x8*)(Vts + r * 256 + c * 16);
        acc_o[0][dblk] = __builtin_amdgcn_mfma_f32_16x16x32_bf16(vf, pb[0].v, acc_o[0][dblk], 0, 0, 0);
        acc_o[1][dblk] = __builtin_amdgcn_mfma_f32_16x16x32_bf16(vf, pb[1].v, acc_o[1][dblk], 0, 0, 0);
      }
      acc_sum[0] = __builtin_amdgcn_mfma_f32_16x16x32_bf16(ones_.v, pb[0].v, acc_sum[0], 0, 0, 0);
      acc_sum[1] = __builtin_amdgcn_mfma_f32_16x16x32_bf16(ones_.v, pb[1].v, acc_sum[1], 0, 0, 0);
      __builtin_amdgcn_s_setprio(0);
    }
    // all ds_reads were consumed by MFMAs (lgkm drained); raw barrier protects cur
    // from being overwritten by next iteration's STAGE before all waves finish reading.
    asm volatile("s_waitcnt lgkmcnt(0)" ::: "memory");
    __builtin_amdgcn_s_barrier();
    __builtin_amdgcn_sched_barrier(0);
  }
#undef STAGE_KV

  const float rinv[2] = {__builtin_amdgcn_rcpf(acc_sum[0][0]),
                         __builtin_amdgcn_rcpf(acc_sum[1][0])};

  // stage Ot -> Os [128 q][64 d] (swizzled), then coalesced global write
#pragma unroll
  for (int qh = 0; qh < 2; ++qh) {
    const int row = wid * 32 + qh * 16 + l15;
#pragma unroll
    for (int dblk = 0; dblk < 4; ++dblk) {
      const unsigned w0 = pkbf(acc_o[qh][dblk][0] * rinv[qh], acc_o[qh][dblk][1] * rinv[qh]);
      const unsigned w1 = pkbf(acc_o[qh][dblk][2] * rinv[qh], acc_o[qh][dblk][3] * rinv[qh]);
      const int cc = dblk * 2 + (g >> 1);    // 16B chunk of d*2 bytes
      char* a = Os + row * 128 + (cc ^ (row & 7)) * 16 + (g & 1) * 8;
      *(uint2*)a = make_uint2(w0, w1);
    }
  }
  __syncthreads();
  const int b = bh >> 4, h = bh & 15;
#pragma unroll
  for (int i = 0; i < 4; ++i) {
    const int L = i * 4096 + t * 16;
    const int r = L >> 7;                    // q row
    const int cc = (L >> 4) & 7;             // logical chunk (d*2 bytes /16)
    const uint4 w = *(const uint4*)(Os + r * 128 + (cc ^ (r & 7)) * 16);
    *(uint4*)&AO[((size_t)(b * Ss + q0 + r) << 10) + h * 64 + cc * 8] = w;
  }
}

// ---------------- output projection: d_out = AO @ Wo^T + bo (fp32 out) ----------------
// 128x64 tiles, 512 blocks, 512 threads (8 waves 4Mx2N), XCD-bijective swizzle.
__global__ __launch_bounds__(512) void out_gemm(char* __restrict__ ws,
                                                const float* __restrict__ bo,
                                                float* __restrict__ outp)
{
  __shared__ __align__(16) char smem[24576];
  char* As = smem;           // [128][64] bf16 (16KB)
  char* Bs = smem + 16384;   // [64][64] bf16 (8KB)
  const bf16* A = (const bf16*)(ws + OFF_AO);
  const bf16* W = (const bf16*)(ws + OFF_WO);
  const int t = threadIdx.x, lane = t & 63, wid = t >> 6;
  const int l15 = lane & 15, g = lane >> 4;
  // swizzle: 512 wgs, xcd = wgid&7 gets nw in [xcd*64, xcd*64+64)
  const int wgid = blockIdx.x + blockIdx.y * 16;
  const int nw = (wgid & 7) * 64 + (wgid >> 3);
  const int m0 = (nw >> 4) * 128, n0 = (nw & 15) * 64;
  const int wm = (wid >> 1) << 5;   // 4 waves M x 2 waves N
  const int wn = (wid & 1) << 5;
  f32x4 acc[2][2] = {};
  for (int kt = 0; kt < 1024; kt += 64) {
    __syncthreads();
#pragma unroll
    for (int i = 0; i < 2; ++i) {
      const int L = i * 8192 + t * 16;
      const int r = L >> 7;
      const int c = ((L >> 4) & 7) ^ (r & 7);
      gll16(A + (size_t)(m0 + r) * 1024 + kt + c * 8, As + i * 8192 + wid * 1024);
    }
    {
      const int L = t * 16;
      const int r = L >> 7;
      const int c = ((L >> 4) & 7) ^ (r & 7);
      gll16(W + (size_t)(n0 + r) * 1024 + kt + c * 8, Bs + t * 16 - (L & 15));
    }
    __syncthreads();
#pragma unroll
    for (int ks = 0; ks < 2; ++ks) {
      bf16x8 af[2], bff[2];
#pragma unroll
      for (int mi = 0; mi < 2; ++mi) {
        const int r = wm + mi * 16 + l15;
        const int c = (ks * 4 + g) ^ (r & 7);
        af[mi] = *(const bf16x8*)(As + r * 128 + c * 16);
      }
#pragma unroll
      for (int ni = 0; ni < 2; ++ni) {
        const int r = wn + ni * 16 + l15;
        const int c = (ks * 4 + g) ^ (r & 7);
        bff[ni] = *(const bf16x8*)(Bs + r * 128 + c * 16);
      }
      __builtin_amdgcn_s_setprio(1);
#pragma unroll
      for (int mi = 0; mi < 2; ++mi)
#pragma unroll
        for (int ni = 0; ni < 2; ++ni)
          acc[mi][ni] = __builtin_amdgcn_mfma_f32_16x16x32_bf16(bff[ni], af[mi], acc[mi][ni], 0, 0, 0);
      __builtin_amdgcn_s_setprio(0);
    }
  }
  // transposed layout: lane&15 = row (token), in-lane = 4 consecutive cols
#pragma unroll
  for (int mi = 0; mi < 2; ++mi) {
    const int row = m0 + wm + mi * 16 + l15;
#pragma unroll
    for (int ni = 0; ni < 2; ++ni) {
      const int col0 = n0 + wn + ni * 16 + g * 4;
      const float4 b4 = *(const float4*)&bo[col0];
      float4 o;
      o.x = acc[mi][ni][0] + b4.x;
      o.y = acc[mi][ni][1] + b4.y;
      o.z = acc[mi][ni][2] + b4.z;
      o.w = acc[mi][ni][3] + b4.w;
      *(float4*)&outp[(size_t)row * Ee + col0] = o;
    }
  }
}

extern "C" void kernel_launch(void* const* d_in, const int* in_sizes, int n_in,
                              void* d_out, int out_size, void* d_ws, size_t ws_size,
                              hipStream_t stream) {
  (void)in_sizes; (void)n_in; (void)out_size; (void)ws_size;
  const float* queries = (const float*)d_in[0];
  const float* keys    = (const float*)d_in[1];
  const float* values  = (const float*)d_in[2];
  const float* Wq = (const float*)d_in[3];
  const float* bq = (const float*)d_in[4];
  const float* Wk = (const float*)d_in[5];
  const float* bk = (const float*)d_in[6];
  const float* Wv = (const float*)d_in[7];
  const float* bv = (const float*)d_in[8];
  const float* Wo = (const float*)d_in[9];
  const float* bo = (const float*)d_in[10];
  const int* indicator = (const int*)d_in[11];
  char* ws = (char*)d_ws;
  float* outp = (float*)d_out;

  convert_kernel<<<4096, 256, 0, stream>>>(queries, keys, values, Wq, Wk, Wv, Wo, indicator, ws);
  proj_gemm<<<dim3(8, 32, 3), 512, 0, stream>>>(ws, bq, bk, bv, indicator);
  attn_kernel<<<512, 256, 0, stream>>>(ws);
  out_gemm<<<dim3(16, 32), 512, 0, stream>>>(ws, bo, outp);
}

// Round 8
// 227.578 us; speedup vs baseline: 1.0584x; 1.0205x over previous
//
#include <hip/hip_runtime.h>
#include <stdint.h>

#define Bb 2
#define Ss 2048
#define Ee 1024
#define Hh 16
#define Dd 64

typedef __bf16 bf16;
typedef __attribute__((ext_vector_type(8))) __bf16 bf16x8;
typedef __attribute__((ext_vector_type(4))) __bf16 bf16x4;
typedef __attribute__((ext_vector_type(4))) float f32x4;

#define MB (1u << 20)
// workspace layout (bf16 regions), total 64 MB
#define OFF_XQ 0u
#define OFF_XK (8u * MB)
#define OFF_XV (16u * MB)
#define OFF_WQ (24u * MB)
#define OFF_WK (26u * MB)
#define OFF_WV (28u * MB)
#define OFF_WO (30u * MB)
#define OFF_Q  (32u * MB)   // [B,H,S,D], prescaled by c1/8 (c1 = +-log2e per indicator)
#define OFF_K  (40u * MB)   // [B,H,S,D]
#define OFF_VT (48u * MB)   // [B,H,D,S]  (transposed V)
#define OFF_AO (56u * MB)   // [B*S, E] attention output

__device__ __forceinline__ void gll16(const void* g, void* lds) {
  __builtin_amdgcn_global_load_lds(
      (const __attribute__((address_space(1))) void*)g,
      (__attribute__((address_space(3))) void*)lds, 16, 0, 0);
}

__device__ __forceinline__ unsigned pkbf(float lo, float hi) {
  unsigned r;
  asm("v_cvt_pk_bf16_f32 %0, %1, %2" : "=v"(r) : "v"(lo), "v"(hi));
  return r;
}
#define PL32SWAP(a, b) asm("v_permlane32_swap_b32 %0, %1" : "+v"(a), "+v"(b))
#define PL16SWAP(a, b) asm("v_permlane16_swap_b32 %0, %1" : "+v"(a), "+v"(b))

// ---------------- convert fp32 -> bf16 (Wq scaled by c1/8), grid-stride x4 ----------------
__global__ __launch_bounds__(256) void convert_kernel(
    const float* __restrict__ q, const float* __restrict__ k, const float* __restrict__ v,
    const float* __restrict__ wq, const float* __restrict__ wk, const float* __restrict__ wv,
    const float* __restrict__ wo, const int* __restrict__ ind, char* __restrict__ ws)
{
  const unsigned base = blockIdx.x * 256u + threadIdx.x;
#pragma unroll
  for (unsigned it = 0; it < 4; ++it) {
    const unsigned i = base + it * 1048576u;   // float4 units, 4194304 total
    const float* src;
    bf16* dst;
    float scale = 1.0f;
    if (i < 3145728u) {                      // queries/keys/values: 1M float4 each
      const unsigned a = i >> 20, j = i & 1048575u;
      src = (a == 0 ? q : a == 1 ? k : v) + (size_t)j * 4;
      dst = (bf16*)(ws + (size_t)a * (8u * MB)) + (size_t)j * 4;
    } else {                                 // Wq,Wk,Wv,Wo: 256K float4 each
      const unsigned i2 = i - 3145728u;
      const unsigned a = i2 >> 18, j = i2 & 262143u;
      src = (a == 0 ? wq : a == 1 ? wk : a == 2 ? wv : wo) + (size_t)j * 4;
      dst = (bf16*)(ws + OFF_WQ + (size_t)a * (2u * MB)) + (size_t)j * 4;
      if (a == 0) {                          // fold 1/sqrt(D) and +-log2e into Wq
        const float c1v = (*ind != 0) ? 1.442695041f : -1.442695041f;
        scale = 0.125f * c1v;
      }
    }
    const float4 f = *(const float4*)src;
    bf16x4 o;
    o[0] = (bf16)(f.x * scale);
    o[1] = (bf16)(f.y * scale);
    o[2] = (bf16)(f.z * scale);
    o[3] = (bf16)(f.w * scale);
    *(bf16x4*)dst = o;
  }
}

// ---------------- 4-wave 128x128x1024 double-buffered GEMM body (C = A * W^T) ----------------
// 256 threads; waves 2M x 2N, each owns 64x64 (balanced FLOP/LDS-byte = 32.7).
// Counted-vmcnt pipeline: next K-step's 8 gll16 stay in flight across the barrier.
// TR=false: acc[mi][ni] = D[m in-lane][n = lane&15]
// TR=true : operands swapped -> acc[mi][ni] = D[n in-lane][m = lane&15] (C^T layout)
template <bool TR>
__device__ __forceinline__ void gemm128_db(
    const bf16* __restrict__ A, const bf16* __restrict__ W,
    char* smem, int m0, int n0, int t, f32x4 (&acc)[4][4])
{
  const int lane = t & 63;
  const int wid = t >> 6;
  const int wm = (wid >> 1) << 6;   // wave sub-tile origin
  const int wn = (wid & 1) << 6;
  const int l15 = lane & 15, g = lane >> 4;
  // buf b: A tile at smem + b*32768 (16KB), B tile at +16384 (16KB)
#define PSTAGE(kt_, b_)                                                               \
  {                                                                                    \
    char* Ab = smem + (b_) * 32768;                                                    \
    char* Bb2 = Ab + 16384;                                                            \
    _Pragma("unroll")                                                                  \
    for (int i = 0; i < 4; ++i) {                                                      \
      const int L = i * 4096 + t * 16;                                                 \
      const int r = L >> 7;                                                            \
      const int c = ((L >> 4) & 7) ^ (r & 7);                                          \
      gll16(A + (size_t)(m0 + r) * 1024 + (kt_) + c * 8, Ab + i * 4096 + wid * 1024);  \
      gll16(W + (size_t)(n0 + r) * 1024 + (kt_) + c * 8, Bb2 + i * 4096 + wid * 1024); \
    }                                                                                  \
  }
  PSTAGE(0, 0);
  for (int step = 0; step < 16; ++step) {
    if (step < 15) {
      PSTAGE((step + 1) * 64, (step + 1) & 1);
      asm volatile("s_waitcnt vmcnt(8)" ::: "memory");   // wait current buf only
    } else {
      asm volatile("s_waitcnt vmcnt(0)" ::: "memory");
    }
    __builtin_amdgcn_s_barrier();
    __builtin_amdgcn_sched_barrier(0);
    char* As = smem + (step & 1) * 32768;
    char* Bs = As + 16384;
#pragma unroll
    for (int ks = 0; ks < 2; ++ks) {
      bf16x8 af[4], bff[4];
#pragma unroll
      for (int mi = 0; mi < 4; ++mi) {
        const int r = wm + mi * 16 + l15;
        const int c = (ks * 4 + g) ^ (r & 7);
        af[mi] = *(const bf16x8*)(As + r * 128 + c * 16);
      }
#pragma unroll
      for (int ni = 0; ni < 4; ++ni) {
        const int r = wn + ni * 16 + l15;
        const int c = (ks * 4 + g) ^ (r & 7);
        bff[ni] = *(const bf16x8*)(Bs + r * 128 + c * 16);
      }
      __builtin_amdgcn_s_setprio(1);
#pragma unroll
      for (int mi = 0; mi < 4; ++mi)
#pragma unroll
        for (int ni = 0; ni < 4; ++ni) {
          if (TR)
            acc[mi][ni] = __builtin_amdgcn_mfma_f32_16x16x32_bf16(bff[ni], af[mi], acc[mi][ni], 0, 0, 0);
          else
            acc[mi][ni] = __builtin_amdgcn_mfma_f32_16x16x32_bf16(af[mi], bff[ni], acc[mi][ni], 0, 0, 0);
        }
      __builtin_amdgcn_s_setprio(0);
    }
    // protect buf from next iteration's STAGE until all waves' ds_reads are done
    asm volatile("s_waitcnt lgkmcnt(0)" ::: "memory");
    __builtin_amdgcn_s_barrier();
    __builtin_amdgcn_sched_barrier(0);
  }
#undef PSTAGE
}

// ---------------- fused Q/K/V projection (grid.z selects q/k/v), 256 threads ----------------
__global__ __launch_bounds__(256) void proj_gemm(
    char* __restrict__ ws, const float* __restrict__ bq,
    const float* __restrict__ bk, const float* __restrict__ bv,
    const int* __restrict__ ind)
{
  __shared__ __align__(16) char smem[65536];
  const int zi = blockIdx.z;
  const bf16* A = (const bf16*)(ws + (zi == 0 ? OFF_XQ : zi == 1 ? OFF_XK : OFF_XV));
  const bf16* W = (const bf16*)(ws + (zi == 0 ? OFF_WQ : zi == 1 ? OFF_WK : OFF_WV));
  const float* bias = zi == 0 ? bq : zi == 1 ? bk : bv;
  bf16* outp = (bf16*)(ws + (zi == 0 ? OFF_Q : zi == 1 ? OFF_K : OFF_VT));
  const float c1v = (*ind != 0) ? 1.442695041f : -1.442695041f;
  const float bscale = (zi == 0) ? 0.125f * c1v : 1.0f;
  const int t = threadIdx.x;
  // swizzle: 256 wgs/z, xcd = wgid&7 gets nw in [xcd*32, xcd*32+32)
  const int wgid = blockIdx.x + blockIdx.y * 8;
  const int nw = (wgid & 7) * 32 + (wgid >> 3);
  const int m0 = (nw >> 3) * 128, n0 = (nw & 7) * 128;
  const int lane = t & 63, wid = t >> 6;
  const int wm = (wid >> 1) << 6, wn = (wid & 1) << 6;
  const int l15 = lane & 15, g = lane >> 4;
  f32x4 acc[4][4] = {};
  if (zi == 2) {
    // V: normal orientation (in-lane = token), store transposed [B,H,D,S] as 8B runs
    gemm128_db<false>(A, W, smem, m0, n0, t, acc);
#pragma unroll
    for (int ni = 0; ni < 4; ++ni) {
      const int col = n0 + wn + ni * 16 + l15;
      const float bvv = bias[col];
      const int h = col >> 6, d = col & 63;
#pragma unroll
      for (int mi = 0; mi < 4; ++mi) {
        const int row0 = m0 + wm + mi * 16 + g * 4;  // token index (r2=0)
        const int b = row0 >> 11, s = row0 & 2047;
        bf16x4 o;
#pragma unroll
        for (int r2 = 0; r2 < 4; ++r2) o[r2] = (bf16)(acc[mi][ni][r2] + bvv);
        *(bf16x4*)&outp[((size_t)((b * Hh + h) * Dd + d) * Ss) + s] = o;
      }
    }
  } else {
    // Q/K: transposed orientation (in-lane = output col), store [B,H,S,D] as 8B runs
    gemm128_db<true>(A, W, smem, m0, n0, t, acc);
#pragma unroll
    for (int mi = 0; mi < 4; ++mi) {
      const int row = m0 + wm + mi * 16 + l15;   // token
      const int b = row >> 11, s = row & 2047;
#pragma unroll
      for (int ni = 0; ni < 4; ++ni) {
        const int col0 = n0 + wn + ni * 16 + g * 4;
        const int h = col0 >> 6, d0 = col0 & 63;
        const float4 b4 = *(const float4*)&bias[col0];
        bf16x4 o;
        o[0] = (bf16)(acc[mi][ni][0] + b4.x * bscale);
        o[1] = (bf16)(acc[mi][ni][1] + b4.y * bscale);
        o[2] = (bf16)(acc[mi][ni][2] + b4.z * bscale);
        o[3] = (bf16)(acc[mi][ni][3] + b4.w * bscale);
        *(bf16x4*)&outp[((size_t)((b * Hh + h) * Ss + s) * Dd) + d0] = o;
      }
    }
  }
}

// ---------------- attention: softmax(sigmoid(QK^T/8)) @ V ----------------
// 512 blocks (XCD-clustered), 4 waves x 32 q-rows (q-tile 128). K/V double-buffered
// (64KB LDS) with COUNTED vmcnt: next tile's 8 gll16 stay in flight across the
// barrier (raw s_barrier, no vmcnt(0) drain). Swapped QK^T; P in registers.
__global__ __launch_bounds__(256, 2) void attn_kernel(char* __restrict__ ws)
{
  __shared__ __align__(16) char smem[65536];
  // buf b at smem + b*32768: K [128 kv][64 d] swz chunk^(r&7) (16KB); Vt [64 d][128 kv] swz (r&15) (16KB)
  char* Os = smem;             // output stage reuses buf0 K region (16KB) at the end
  const int t = threadIdx.x, lane = t & 63, wid = t >> 6;
  const int g = lane >> 4, l15 = lane & 15;
  // XCD-clustered decode: xcd = lin&7 serves bh in [xcd*4, xcd*4+4) -> K/V L2-resident
  const int lin = blockIdx.x;
  const int j = lin >> 3;
  const int bh = ((lin & 7) << 2) + (j & 3);
  const int q0 = (j >> 2) << 7;
  const bf16* Qg  = (const bf16*)(ws + OFF_Q)  + (size_t)bh * Ss * Dd;
  const bf16* Kg  = (const bf16*)(ws + OFF_K)  + (size_t)bh * Ss * Dd;
  const bf16* Vtg = (const bf16*)(ws + OFF_VT) + (size_t)bh * Ss * Dd;
  bf16* AO = (bf16*)(ws + OFF_AO);

  // Q fragments (B operand of swapped mfma) straight from global; wave covers 32 q-rows
  bf16x8 qf[2][2];
#pragma unroll
  for (int qh = 0; qh < 2; ++qh)
#pragma unroll
    for (int ks = 0; ks < 2; ++ks)
      qf[qh][ks] = *(const bf16x8*)(Qg + (size_t)(q0 + wid * 32 + qh * 16 + l15) * Dd + ks * 32 + g * 8);

  f32x4 acc_o[2][4] = {};   // [qh][dblk]: Ot[d][q], d = dblk*16+g*4+r2, q = l15
  f32x4 acc_sum[2] = {};    // row sums via ones-MFMA
  union { unsigned u[4]; bf16x8 v; } ones_;
#pragma unroll
  for (int jj = 0; jj < 4; ++jj) ones_.u[jj] = 0x3F803F80u;  // bf16 1.0 pairs

  // staging helper: 8 gll16 per thread (K tile + Vt tile)
#define STAGE_KV(kt_, buf_)                                                         \
  {                                                                                  \
    char* Kb = (buf_);                                                               \
    char* Vb = (buf_) + 16384;                                                       \
    _Pragma("unroll")                                                                \
    for (int i = 0; i < 4; ++i) {                                                    \
      const int L = i * 4096 + t * 16;                                               \
      const int rk = L >> 7;                                                         \
      const int ck = ((L >> 4) & 7) ^ (rk & 7);                                      \
      gll16(Kg + (size_t)((kt_) + rk) * Dd + ck * 8, Kb + i * 4096 + wid * 1024);    \
      const int rv = L >> 8;                                                         \
      const int cv = ((L >> 4) & 15) ^ (rv & 15);                                    \
      gll16(Vtg + (size_t)rv * Ss + (kt_) + cv * 8, Vb + i * 4096 + wid * 1024);     \
    }                                                                                \
  }

  STAGE_KV(0, smem);

  for (int ti = 0; ti < 16; ++ti) {
    char* cur = smem + (ti & 1) * 32768;
    char* nxt = smem + ((ti & 1) ^ 1) * 32768;
    if (ti < 15) {
      STAGE_KV((ti + 1) * 128, nxt);
      // wait only the 8 oldest (cur's) loads; nxt's 8 stay in flight across barrier
      asm volatile("s_waitcnt vmcnt(8)" ::: "memory");
    } else {
      asm volatile("s_waitcnt vmcnt(0)" ::: "memory");
    }
    __builtin_amdgcn_s_barrier();
    __builtin_amdgcn_sched_barrier(0);
    char* Ks = cur;
    char* Vts = cur + 16384;

    // St = K Q^T : St[qh][kv][q], kv = ni*16 + g*4 + r2, q = l15; init log2(ln2)
    f32x4 st[2][8];
#pragma unroll
    for (int qh = 0; qh < 2; ++qh)
#pragma unroll
      for (int ni = 0; ni < 8; ++ni)
        st[qh][ni] = (f32x4){-0.52876637f, -0.52876637f, -0.52876637f, -0.52876637f};
    __builtin_amdgcn_s_setprio(1);
#pragma unroll
    for (int ks = 0; ks < 2; ++ks) {
#pragma unroll
      for (int ni = 0; ni < 8; ++ni) {
        const int r = ni * 16 + l15;
        const int c = (ks * 4 + g) ^ (r & 7);
        const bf16x8 kf = *(const bf16x8*)(Ks + r * 128 + c * 16);
        st[0][ni] = __builtin_amdgcn_mfma_f32_16x16x32_bf16(kf, qf[0][ks], st[0][ni], 0, 0, 0);
        st[1][ni] = __builtin_amdgcn_mfma_f32_16x16x32_bf16(kf, qf[1][ks], st[1][ni], 0, 0, 0);
      }
    }
    __builtin_amdgcn_s_setprio(0);

    // per 32-kv block: p = exp2(rcp(ln2 + exp2(st))); pack; permlane into PV B-frag
#pragma unroll
    for (int kb = 0; kb < 4; ++kb) {
      union { unsigned u[4]; bf16x8 v; } pb[2];
#pragma unroll
      for (int qh = 0; qh < 2; ++qh) {
        float p[2][4];
#pragma unroll
        for (int e = 0; e < 2; ++e)
#pragma unroll
          for (int r2 = 0; r2 < 4; ++r2) {
            const float ex = __builtin_amdgcn_exp2f(st[qh][2 * kb + e][r2]);
            const float tt = __builtin_amdgcn_rcpf(0.69314718f + ex);
            p[e][r2] = __builtin_amdgcn_exp2f(tt);
          }
        unsigned E0 = pkbf(p[0][0], p[0][1]);
        unsigned E1 = pkbf(p[0][2], p[0][3]);
        unsigned O0 = pkbf(p[1][0], p[1][1]);
        unsigned O1 = pkbf(p[1][2], p[1][3]);
        PL32SWAP(E0, O0);
        PL16SWAP(E0, O0);
        PL32SWAP(E1, O1);
        PL16SWAP(E1, O1);
        pb[qh].u[0] = E0; pb[qh].u[1] = E1; pb[qh].u[2] = O0; pb[qh].u[3] = O1;
      }
      __builtin_amdgcn_s_setprio(1);
#pragma unroll
      for (int dblk = 0; dblk < 4; ++dblk) {
        const int r = dblk * 16 + l15;
        const int c = (kb * 4 + g) ^ (r & 15);
        const bf16x8 vf = *(const bf16x8*)(Vts + r * 256 + c * 16);
        acc_o[0][dblk] = __builtin_amdgcn_mfma_f32_16x16x32_bf16(vf, pb[0].v, acc_o[0][dblk], 0, 0, 0);
        acc_o[1][dblk] = __builtin_amdgcn_mfma_f32_16x16x32_bf16(vf, pb[1].v, acc_o[1][dblk], 0, 0, 0);
      }
      acc_sum[0] = __builtin_amdgcn_mfma_f32_16x16x32_bf16(ones_.v, pb[0].v, acc_sum[0], 0, 0, 0);
      acc_sum[1] = __builtin_amdgcn_mfma_f32_16x16x32_bf16(ones_.v, pb[1].v, acc_sum[1], 0, 0, 0);
      __builtin_amdgcn_s_setprio(0);
    }
    // all ds_reads were consumed by MFMAs (lgkm drained); raw barrier protects cur
    // from being overwritten by next iteration's STAGE before all waves finish reading.
    asm volatile("s_waitcnt lgkmcnt(0)" ::: "memory");
    __builtin_amdgcn_s_barrier();
    __builtin_amdgcn_sched_barrier(0);
  }
#undef STAGE_KV

  const float rinv[2] = {__builtin_amdgcn_rcpf(acc_sum[0][0]),
                         __builtin_amdgcn_rcpf(acc_sum[1][0])};

  // stage Ot -> Os [128 q][64 d] (swizzled), then coalesced global write
#pragma unroll
  for (int qh = 0; qh < 2; ++qh) {
    const int row = wid * 32 + qh * 16 + l15;
#pragma unroll
    for (int dblk = 0; dblk < 4; ++dblk) {
      const unsigned w0 = pkbf(acc_o[qh][dblk][0] * rinv[qh], acc_o[qh][dblk][1] * rinv[qh]);
      const unsigned w1 = pkbf(acc_o[qh][dblk][2] * rinv[qh], acc_o[qh][dblk][3] * rinv[qh]);
      const int cc = dblk * 2 + (g >> 1);    // 16B chunk of d*2 bytes
      char* a = Os + row * 128 + (cc ^ (row & 7)) * 16 + (g & 1) * 8;
      *(uint2*)a = make_uint2(w0, w1);
    }
  }
  __syncthreads();
  const int b = bh >> 4, h = bh & 15;
#pragma unroll
  for (int i = 0; i < 4; ++i) {
    const int L = i * 4096 + t * 16;
    const int r = L >> 7;                    // q row
    const int cc = (L >> 4) & 7;             // logical chunk (d*2 bytes /16)
    const uint4 w = *(const uint4*)(Os + r * 128 + (cc ^ (r & 7)) * 16);
    *(uint4*)&AO[((size_t)(b * Ss + q0 + r) << 10) + h * 64 + cc * 8] = w;
  }
}

// ---------------- output projection: d_out = AO @ Wo^T + bo (fp32 out) ----------------
// 128x64 tiles, 512 blocks, 256 threads (4 waves 2Mx2N), counted-vmcnt dbuf.
__global__ __launch_bounds__(256) void out_gemm(char* __restrict__ ws,
                                                const float* __restrict__ bo,
                                                float* __restrict__ outp)
{
  __shared__ __align__(16) char smem[49152];
  // buf b at smem + b*24576: A [128][64] bf16 (16KB), B [64][64] bf16 (8KB)
  const bf16* A = (const bf16*)(ws + OFF_AO);
  const bf16* W = (const bf16*)(ws + OFF_WO);
  const int t = threadIdx.x, lane = t & 63, wid = t >> 6;
  const int l15 = lane & 15, g = lane >> 4;
  // swizzle: 512 wgs, xcd = wgid&7 gets nw in [xcd*64, xcd*64+64)
  const int wgid = blockIdx.x + blockIdx.y * 16;
  const int nw = (wgid & 7) * 64 + (wgid >> 3);
  const int m0 = (nw >> 4) * 128, n0 = (nw & 15) * 64;
  const int wm = (wid >> 1) << 6;   // 2 waves M x 2 waves N; wave tile 64x32
  const int wn = (wid & 1) << 5;
  f32x4 acc[4][2] = {};
#define OSTAGE(kt_, b_)                                                               \
  {                                                                                    \
    char* Ab = smem + (b_) * 24576;                                                    \
    char* Bb2 = Ab + 16384;                                                            \
    _Pragma("unroll")                                                                  \
    for (int i = 0; i < 4; ++i) {                                                      \
      const int L = i * 4096 + t * 16;                                                 \
      const int r = L >> 7;                                                            \
      const int c = ((L >> 4) & 7) ^ (r & 7);                                          \
      gll16(A + (size_t)(m0 + r) * 1024 + (kt_) + c * 8, Ab + i * 4096 + wid * 1024);  \
    }                                                                                  \
    _Pragma("unroll")                                                                  \
    for (int i = 0; i < 2; ++i) {                                                      \
      const int L = i * 4096 + t * 16;                                                 \
      const int r = L >> 7;                                                            \
      const int c = ((L >> 4) & 7) ^ (r & 7);                                          \
      gll16(W + (size_t)(n0 + r) * 1024 + (kt_) + c * 8, Bb2 + i * 4096 + wid * 1024); \
    }                                                                                  \
  }
  OSTAGE(0, 0);
  for (int step = 0; step < 16; ++step) {
    if (step < 15) {
      OSTAGE((step + 1) * 64, (step + 1) & 1);
      asm volatile("s_waitcnt vmcnt(6)" ::: "memory");
    } else {
      asm volatile("s_waitcnt vmcnt(0)" ::: "memory");
    }
    __builtin_amdgcn_s_barrier();
    __builtin_amdgcn_sched_barrier(0);
    char* As = smem + (step & 1) * 24576;
    char* Bs = As + 16384;
#pragma unroll
    for (int ks = 0; ks < 2; ++ks) {
      bf16x8 af[4], bff[2];
#pragma unroll
      for (int mi = 0; mi < 4; ++mi) {
        const int r = wm + mi * 16 + l15;
        const int c = (ks * 4 + g) ^ (r & 7);
        af[mi] = *(const bf16x8*)(As + r * 128 + c * 16);
      }
#pragma unroll
      for (int ni = 0; ni < 2; ++ni) {
        const int r = wn + ni * 16 + l15;
        const int c = (ks * 4 + g) ^ (r & 7);
        bff[ni] = *(const bf16x8*)(Bs + r * 128 + c * 16);
      }
      __builtin_amdgcn_s_setprio(1);
#pragma unroll
      for (int mi = 0; mi < 4; ++mi)
#pragma unroll
        for (int ni = 0; ni < 2; ++ni)
          acc[mi][ni] = __builtin_amdgcn_mfma_f32_16x16x32_bf16(bff[ni], af[mi], acc[mi][ni], 0, 0, 0);
      __builtin_amdgcn_s_setprio(0);
    }
    asm volatile("s_waitcnt lgkmcnt(0)" ::: "memory");
    __builtin_amdgcn_s_barrier();
    __builtin_amdgcn_sched_barrier(0);
  }
#undef OSTAGE
  // transposed layout: lane&15 = row (token), in-lane = 4 consecutive cols
#pragma unroll
  for (int mi = 0; mi < 4; ++mi) {
    const int row = m0 + wm + mi * 16 + l15;
#pragma unroll
    for (int ni = 0; ni < 2; ++ni) {
      const int col0 = n0 + wn + ni * 16 + g * 4;
      const float4 b4 = *(const float4*)&bo[col0];
      float4 o;
      o.x = acc[mi][ni][0] + b4.x;
      o.y = acc[mi][ni][1] + b4.y;
      o.z = acc[mi][ni][2] + b4.z;
      o.w = acc[mi][ni][3] + b4.w;
      *(float4*)&outp[(size_t)row * Ee + col0] = o;
    }
  }
}

extern "C" void kernel_launch(void* const* d_in, const int* in_sizes, int n_in,
                              void* d_out, int out_size, void* d_ws, size_t ws_size,
                              hipStream_t stream) {
  (void)in_sizes; (void)n_in; (void)out_size; (void)ws_size;
  const float* queries = (const float*)d_in[0];
  const float* keys    = (const float*)d_in[1];
  const float* values  = (const float*)d_in[2];
  const float* Wq = (const float*)d_in[3];
  const float* bq = (const float*)d_in[4];
  const float* Wk = (const float*)d_in[5];
  const float* bk = (const float*)d_in[6];
  const float* Wv = (const float*)d_in[7];
  const float* bv = (const float*)d_in[8];
  const float* Wo = (const float*)d_in[9];
  const float* bo = (const float*)d_in[10];
  const int* indicator = (const int*)d_in[11];
  char* ws = (char*)d_ws;
  float* outp = (float*)d_out;

  convert_kernel<<<4096, 256, 0, stream>>>(queries, keys, values, Wq, Wk, Wv, Wo, indicator, ws);
  proj_gemm<<<dim3(8, 32, 3), 256, 0, stream>>>(ws, bq, bk, bv, indicator);
  attn_kernel<<<512, 256, 0, stream>>>(ws);
  out_gemm<<<dim3(16, 32), 256, 0, stream>>>(ws, bo, outp);
}